// Round 1
// baseline (202.457 us; speedup 1.0000x reference)
//
#include <hip/hip_runtime.h>
#include <math.h>

#define HIDDEN 256
#define NHEADS 8
#define HEAD 32
#define NTOK 2048      // tokens per batch (8*16*16)
#define MROWS 8192     // 4 * 2048

typedef __attribute__((ext_vector_type(8))) __bf16 bf16x8;
typedef __attribute__((ext_vector_type(4))) float f32x4;

static __device__ __forceinline__ f32x4 mfma16(bf16x8 a, bf16x8 b, f32x4 c) {
    return __builtin_amdgcn_mfma_f32_16x16x32_bf16(a, b, c, 0, 0, 0);
}

// ---------------- kernel 0a: x fp32 -> bf16 ----------------
__global__ void k_cvt_x(const float* __restrict__ x, __bf16* __restrict__ xb) {
    int i = (blockIdx.x * blockDim.x + threadIdx.x) * 4;
    float4 v = *(const float4*)(x + i);
    xb[i + 0] = (__bf16)v.x;
    xb[i + 1] = (__bf16)v.y;
    xb[i + 2] = (__bf16)v.z;
    xb[i + 3] = (__bf16)v.w;
}

// ---------------- kernel 0b: W fp32 -> bf16, transposed (N x K) ----------------
__global__ void k_cvt_w(const float* __restrict__ w0, const float* __restrict__ w1,
                        const float* __restrict__ w2, const float* __restrict__ w3,
                        __bf16* __restrict__ t0, __bf16* __restrict__ t1,
                        __bf16* __restrict__ t2, __bf16* __restrict__ t3) {
    int wsel = blockIdx.x >> 8;          // 0..3
    int i = (blockIdx.x & 255) * 256 + threadIdx.x;   // 0..65535
    const float* w = (wsel == 0) ? w0 : (wsel == 1) ? w1 : (wsel == 2) ? w2 : w3;
    __bf16* t = (wsel == 0) ? t0 : (wsel == 1) ? t1 : (wsel == 2) ? t2 : t3;
    int n = i >> 8, k = i & 255;
    t[i] = (__bf16)w[k * 256 + n];       // t[n][k] = W[k][n]
}

// ---------------- kernel 1: fused QKV projection ----------------
// wave-per-16x16 output tile. tiles: mt in [0,512) x nt in [0,48)
// nt 0-15 -> Q cols, 16-31 -> K cols, 32-47 -> V cols
__global__ __launch_bounds__(256) void k_qkv(const __bf16* __restrict__ xb,
                                             const __bf16* __restrict__ wqT,
                                             const __bf16* __restrict__ wkT,
                                             const __bf16* __restrict__ wvT,
                                             __bf16* __restrict__ qb,
                                             __bf16* __restrict__ kb,
                                             __bf16* __restrict__ vb) {
    int wid = blockIdx.x * 4 + (threadIdx.x >> 6);
    int lane = threadIdx.x & 63;
    int nt = wid % 48, mt = wid / 48;
    int mbase = mt * 16;
    int lm = lane & 15, lk = (lane >> 4) * 8;
    const __bf16* wT; int ncol0;
    if (nt < 16)      { wT = wqT; ncol0 = nt * 16; }
    else if (nt < 32) { wT = wkT; ncol0 = (nt - 16) * 16; }
    else              { wT = wvT; ncol0 = (nt - 32) * 16; }

    f32x4 acc = {0.f, 0.f, 0.f, 0.f};
    const __bf16* arow = xb + (size_t)(mbase + lm) * 256 + lk;
    const __bf16* brow = wT + (size_t)(ncol0 + lm) * 256 + lk;
#pragma unroll
    for (int kk = 0; kk < 8; ++kk) {
        bf16x8 a = *(const bf16x8*)(arow + kk * 32);
        bf16x8 b = *(const bf16x8*)(brow + kk * 32);
        acc = mfma16(a, b, acc);
    }
    int col = ncol0 + lm;
    int h = col >> 5, d = col & 31;
#pragma unroll
    for (int r = 0; r < 4; ++r) {
        int row = mbase + ((lane >> 4) << 2) + r;
        int b_ = row >> 11, n = row & 2047;
        __bf16 val = (__bf16)acc[r];
        if (nt < 16)      qb[((size_t)(b_ * 8 + h) * 2048 + n) * 32 + d] = val;
        else if (nt < 32) kb[((size_t)(b_ * 8 + h) * 2048 + n) * 32 + d] = val;
        else              vb[((size_t)(b_ * 8 + h) * 32 + d) * 2048 + n] = val; // V transposed
    }
}

// ---------------- kernel 2: flash attention with 3D rel-pos bias ----------------
// grid: 1024 blocks = 32 (b,h) * 32 q-tiles(64 rows); 4 waves, each owns 16 q-rows
__global__ __launch_bounds__(256) void k_attn(const __bf16* __restrict__ qb,
                                              const __bf16* __restrict__ kb,
                                              const __bf16* __restrict__ vb,
                                              const float* __restrict__ bias_table,
                                              __bf16* __restrict__ attn) {
    int bid = blockIdx.x;
    int bh = bid >> 5;          // 0..31
    int qt = bid & 31;          // 0..31
    int b_ = bh >> 3, h = bh & 7;
    int wv = threadIdx.x >> 6;  // 0..3
    int lane = threadIdx.x & 63;
    int lm = lane & 15;
    int lg = lane >> 4;         // 0..3
    int lk = lg * 8;
    int qrow0 = qt * 64 + wv * 16;

    const __bf16* qbase = qb + (size_t)bh * NTOK * 32;
    const __bf16* kbase = kb + (size_t)bh * NTOK * 32;
    const __bf16* vbase = vb + (size_t)bh * 32 * NTOK;
    const float* bt = bias_table + h * 15 * 31 * 31;

    // Q fragment (fixed for whole kernel): A[row=lm][k=lk..lk+7]
    bf16x8 qf = *(const bf16x8*)(qbase + (size_t)(qrow0 + lm) * 32 + lk);

    int dn[4], hn[4], wn[4];
#pragma unroll
    for (int r = 0; r < 4; ++r) {
        int row = qrow0 + lg * 4 + r;
        dn[r] = row >> 8; hn[r] = (row >> 4) & 15; wn[r] = row & 15;
    }

    float m_run[4], l_run[4];
    f32x4 o0 = {0.f, 0.f, 0.f, 0.f}, o1 = {0.f, 0.f, 0.f, 0.f};
#pragma unroll
    for (int r = 0; r < 4; ++r) { m_run[r] = -INFINITY; l_run[r] = 0.f; }

    __shared__ __bf16 pbuf[4][16][48];   // stride 96B: 16B-aligned rows for ds_read_b128
    const float scale = 0.17677669529663687f;  // 1/sqrt(32)

    for (int kt = 0; kt < 64; ++kt) {
        int t0 = kt * 32;
        bf16x8 kf0 = *(const bf16x8*)(kbase + (size_t)(t0 + lm) * 32 + lk);
        bf16x8 kf1 = *(const bf16x8*)(kbase + (size_t)(t0 + 16 + lm) * 32 + lk);
        f32x4 z = {0.f, 0.f, 0.f, 0.f};
        f32x4 s0 = mfma16(qf, kf0, z);
        f32x4 s1 = mfma16(qf, kf1, z);

        int m0 = t0 + lm, m1 = t0 + 16 + lm;
        int dm0 = m0 >> 8, hm0 = (m0 >> 4) & 15, wm0 = m0 & 15;
        int dm1 = m1 >> 8, hm1 = (m1 >> 4) & 15, wm1 = m1 & 15;
#pragma unroll
        for (int r = 0; r < 4; ++r) {
            float v0 = s0[r] * scale + bt[(dn[r] - dm0 + 7) * 961 + (hn[r] - hm0 + 15) * 31 + (wn[r] - wm0 + 15)];
            float v1 = s1[r] * scale + bt[(dn[r] - dm1 + 7) * 961 + (hn[r] - hm1 + 15) * 31 + (wn[r] - wm1 + 15)];
            float tmax = fmaxf(v0, v1);
            tmax = fmaxf(tmax, __shfl_xor(tmax, 1));
            tmax = fmaxf(tmax, __shfl_xor(tmax, 2));
            tmax = fmaxf(tmax, __shfl_xor(tmax, 4));
            tmax = fmaxf(tmax, __shfl_xor(tmax, 8));
            float mnew = fmaxf(m_run[r], tmax);
            float alpha = __expf(m_run[r] - mnew);
            float p0 = __expf(v0 - mnew);
            float p1 = __expf(v1 - mnew);
            float rs = p0 + p1;
            rs += __shfl_xor(rs, 1);
            rs += __shfl_xor(rs, 2);
            rs += __shfl_xor(rs, 4);
            rs += __shfl_xor(rs, 8);
            l_run[r] = l_run[r] * alpha + rs;
            m_run[r] = mnew;
            o0[r] *= alpha; o1[r] *= alpha;
            int row = lg * 4 + r;
            pbuf[wv][row][lm]      = (__bf16)p0;
            pbuf[wv][row][16 + lm] = (__bf16)p1;
        }
        // P fragment: A[row=lm][k=lk..lk+7] (wave-internal LDS round-trip, no barrier needed)
        bf16x8 pf  = *(const bf16x8*)(&pbuf[wv][lm][lk]);
        bf16x8 vf0 = *(const bf16x8*)(vbase + (size_t)lm * NTOK + t0 + lk);
        bf16x8 vf1 = *(const bf16x8*)(vbase + (size_t)(16 + lm) * NTOK + t0 + lk);
        o0 = mfma16(pf, vf0, o0);
        o1 = mfma16(pf, vf1, o1);
    }
#pragma unroll
    for (int r = 0; r < 4; ++r) {
        float inv = 1.0f / l_run[r];
        int row = qrow0 + lg * 4 + r;
        size_t base = ((size_t)b_ * 2048 + row) * 256 + h * 32;
        attn[base + lm]      = (__bf16)(o0[r] * inv);
        attn[base + 16 + lm] = (__bf16)(o1[r] * inv);
    }
}

// ---------------- kernel 3: output projection -> fp32 ----------------
__global__ __launch_bounds__(256) void k_out(const __bf16* __restrict__ attn,
                                             const __bf16* __restrict__ woT,
                                             float* __restrict__ out) {
    int wid = blockIdx.x * 4 + (threadIdx.x >> 6);
    int lane = threadIdx.x & 63;
    int nt = wid & 15, mt = wid >> 4;
    int lm = lane & 15, lk = (lane >> 4) * 8;
    f32x4 acc = {0.f, 0.f, 0.f, 0.f};
    const __bf16* arow = attn + (size_t)(mt * 16 + lm) * 256 + lk;
    const __bf16* brow = woT + (size_t)(nt * 16 + lm) * 256 + lk;
#pragma unroll
    for (int kk = 0; kk < 8; ++kk) {
        bf16x8 a = *(const bf16x8*)(arow + kk * 32);
        bf16x8 b = *(const bf16x8*)(brow + kk * 32);
        acc = mfma16(a, b, acc);
    }
    int col = nt * 16 + lm;
#pragma unroll
    for (int r = 0; r < 4; ++r) {
        int row = mt * 16 + ((lane >> 4) << 2) + r;
        out[(size_t)row * 256 + col] = acc[r];
    }
}

extern "C" void kernel_launch(void* const* d_in, const int* in_sizes, int n_in,
                              void* d_out, int out_size, void* d_ws, size_t ws_size,
                              hipStream_t stream) {
    const float* x    = (const float*)d_in[0];
    const float* Wq   = (const float*)d_in[1];
    const float* Wk   = (const float*)d_in[2];
    const float* Wv   = (const float*)d_in[3];
    const float* Wo   = (const float*)d_in[4];
    const float* bias = (const float*)d_in[5];
    float* out = (float*)d_out;

    __bf16* ws  = (__bf16*)d_ws;
    __bf16* xb  = ws;                       // 8192*256      = 2,097,152
    __bf16* wqT = xb  + 2097152;            // 65536
    __bf16* wkT = wqT + 65536;
    __bf16* wvT = wkT + 65536;
    __bf16* woT = wvT + 65536;
    __bf16* qb  = woT + 65536;              // (b,h,n,32)    = 2,097,152
    __bf16* kb  = qb  + 2097152;            // (b,h,n,32)
    __bf16* vb  = kb  + 2097152;            // (b,h,32,n)  V transposed
    __bf16* att = vb  + 2097152;            // (b,n,256)

    k_cvt_x<<<2048, 256, 0, stream>>>(x, xb);
    k_cvt_w<<<1024, 256, 0, stream>>>(Wq, Wk, Wv, Wo, wqT, wkT, wvT, woT);
    k_qkv<<<6144, 256, 0, stream>>>(xb, wqT, wkT, wvT, qb, kb, vb);
    k_attn<<<1024, 256, 0, stream>>>(qb, kb, vb, bias, att);
    k_out<<<2048, 256, 0, stream>>>(att, woT, out);
}

// Round 2
// 163.810 us; speedup vs baseline: 1.2359x; 1.2359x over previous
//
#include <hip/hip_runtime.h>
#include <math.h>

#define HIDDEN 256
#define NHEADS 8
#define HEAD 32
#define NTOK 2048      // tokens per batch (8*16*16)
#define MROWS 8192     // 4 * 2048
#define NBIAS 115320   // 8 * 15 * 31 * 31

typedef __attribute__((ext_vector_type(8))) __bf16 bf16x8;
typedef __attribute__((ext_vector_type(4))) float f32x4;

static __device__ __forceinline__ f32x4 mfma16(bf16x8 a, bf16x8 b, f32x4 c) {
    return __builtin_amdgcn_mfma_f32_16x16x32_bf16(a, b, c, 0, 0, 0);
}

static __device__ __forceinline__ float fast_exp2(float x) {
#if __has_builtin(__builtin_amdgcn_exp2f)
    return __builtin_amdgcn_exp2f(x);
#else
    return exp2f(x);
#endif
}

// ---------------- kernel 0a: x fp32 -> bf16 ----------------
__global__ void k_cvt_x(const float* __restrict__ x, __bf16* __restrict__ xb) {
    int i = (blockIdx.x * blockDim.x + threadIdx.x) * 4;
    float4 v = *(const float4*)(x + i);
    xb[i + 0] = (__bf16)v.x;
    xb[i + 1] = (__bf16)v.y;
    xb[i + 2] = (__bf16)v.z;
    xb[i + 3] = (__bf16)v.w;
}

// ---------------- kernel 0b: W fp32 -> bf16, transposed (N x K) ----------------
__global__ void k_cvt_w(const float* __restrict__ w0, const float* __restrict__ w1,
                        const float* __restrict__ w2, const float* __restrict__ w3,
                        __bf16* __restrict__ t0, __bf16* __restrict__ t1,
                        __bf16* __restrict__ t2, __bf16* __restrict__ t3) {
    int wsel = blockIdx.x >> 8;          // 0..3
    int i = (blockIdx.x & 255) * 256 + threadIdx.x;   // 0..65535
    const float* w = (wsel == 0) ? w0 : (wsel == 1) ? w1 : (wsel == 2) ? w2 : w3;
    __bf16* t = (wsel == 0) ? t0 : (wsel == 1) ? t1 : (wsel == 2) ? t2 : t3;
    int n = i >> 8, k = i & 255;
    t[i] = (__bf16)w[k * 256 + n];       // t[n][k] = W[k][n]
}

// ---------------- kernel 0c: bias table * log2(e) -> fp32 ----------------
__global__ void k_cvt_bias(const float* __restrict__ bias, float* __restrict__ btx) {
    int i = blockIdx.x * 256 + threadIdx.x;
    if (i < NBIAS) btx[i] = bias[i] * 1.4426950408889634f;
}

// ---------------- kernel 1: fused QKV projection ----------------
// wave computes a 16x64 output strip: mt in [0,512), g in [0,12)
// g>>2 selects {Q,K,V}; (g&3)*64 is the column base. Q pre-scaled by log2e/sqrt(32).
__global__ __launch_bounds__(256) void k_qkv(const __bf16* __restrict__ xb,
                                             const __bf16* __restrict__ wqT,
                                             const __bf16* __restrict__ wkT,
                                             const __bf16* __restrict__ wvT,
                                             __bf16* __restrict__ qb,
                                             __bf16* __restrict__ kb,
                                             __bf16* __restrict__ vb) {
    int wid = blockIdx.x * 4 + (threadIdx.x >> 6);   // 0..6143
    int lane = threadIdx.x & 63;
    int g = wid % 12, mt = wid / 12;
    int lm = lane & 15, lg = lane >> 4, lk = lg * 8;
    int which = g >> 2;
    int nc0 = (g & 3) * 64;
    const __bf16* wT = (which == 0) ? wqT : (which == 1) ? wkT : wvT;

    f32x4 acc[4];
#pragma unroll
    for (int j = 0; j < 4; ++j) acc[j] = (f32x4){0.f, 0.f, 0.f, 0.f};

    const __bf16* arow = xb + (size_t)(mt * 16 + lm) * 256 + lk;
    const __bf16* brow = wT + (size_t)(nc0 + lm) * 256 + lk;
#pragma unroll
    for (int kk = 0; kk < 8; ++kk) {
        bf16x8 a = *(const bf16x8*)(arow + kk * 32);
#pragma unroll
        for (int j = 0; j < 4; ++j) {
            bf16x8 b = *(const bf16x8*)(brow + (size_t)j * 16 * 256 + kk * 32);
            acc[j] = mfma16(a, b, acc[j]);
        }
    }
    const float QS = 0.17677669529663687f * 1.4426950408889634f;  // 1/sqrt(32) * log2(e)
#pragma unroll
    for (int j = 0; j < 4; ++j) {
        int col = nc0 + j * 16 + lm;
        int h = col >> 5, d = col & 31;
#pragma unroll
        for (int r = 0; r < 4; ++r) {
            int row = mt * 16 + lg * 4 + r;
            int b_ = row >> 11, n = row & 2047;
            if (which == 0)      qb[((size_t)(b_ * 8 + h) * 2048 + n) * 32 + d] = (__bf16)(acc[j][r] * QS);
            else if (which == 1) kb[((size_t)(b_ * 8 + h) * 2048 + n) * 32 + d] = (__bf16)acc[j][r];
            else                 vb[((size_t)(b_ * 8 + h) * 32 + d) * 2048 + n] = (__bf16)acc[j][r]; // V^T
        }
    }
}

// ---------------- kernel 2: flash attention, fixed-reference softmax ----------------
// p = exp2( (s*scale + b - C)*log2e )  with scale,log2e folded into Q and -C*log2e
// folded into the MFMA accumulator init. No running max, no rescale, no shuffles in loop.
__global__ __launch_bounds__(256) void k_attn(const __bf16* __restrict__ qb,
                                              const __bf16* __restrict__ kb,
                                              const __bf16* __restrict__ vb,
                                              const float* __restrict__ btx,
                                              __bf16* __restrict__ attn) {
    int bid = blockIdx.x;
    int bh = bid >> 5;          // 0..31
    int qt = bid & 31;          // 0..31
    int b_ = bh >> 3, h = bh & 7;
    int wv = threadIdx.x >> 6;  // 0..3
    int lane = threadIdx.x & 63;
    int lm = lane & 15;
    int lg = lane >> 4;         // 0..3
    int lk = lg * 8;
    int qrow0 = qt * 64 + wv * 16;

    const __bf16* qbase = qb + (size_t)bh * NTOK * 32;
    const __bf16* kbase = kb + (size_t)bh * NTOK * 32;
    const __bf16* vbase = vb + (size_t)bh * 32 * NTOK;
    const float* bt = btx + h * 15 * 31 * 31;

    // Q fragment (fixed for whole kernel): A[row=lm][k=lk..lk+7]
    bf16x8 qf = *(const bf16x8*)(qbase + (size_t)(qrow0 + lm) * 32 + lk);

    // additive bias decomposition: idx = qidx[r] + koff(col)
    int qidx[4];
#pragma unroll
    for (int r = 0; r < 4; ++r) {
        int row = qrow0 + lg * 4 + r;
        qidx[r] = (row >> 8) * 961 + ((row >> 4) & 15) * 31 + (row & 15) + 7207;
    }

    float lsum[4] = {0.f, 0.f, 0.f, 0.f};
    f32x4 o0 = {0.f, 0.f, 0.f, 0.f}, o1 = {0.f, 0.f, 0.f, 0.f};
    const float NEGCL = -28.853900817779268f;   // -20 * log2(e)
    const f32x4 cinit = {NEGCL, NEGCL, NEGCL, NEGCL};

    __shared__ __attribute__((aligned(16))) __bf16 pbuf[4][16][48];
    __bf16* pb = &pbuf[wv][0][0];

    for (int kt = 0; kt < 64; ++kt) {
        int t0 = kt * 32;
        bf16x8 kf0 = *(const bf16x8*)(kbase + (size_t)(t0 + lm) * 32 + lk);
        bf16x8 kf1 = *(const bf16x8*)(kbase + (size_t)(t0 + 16 + lm) * 32 + lk);
        int m0 = t0 + lm, m1 = m0 + 16;
        int koff0 = -((m0 >> 8) * 961 + ((m0 >> 4) & 15) * 31 + (m0 & 15));
        int koff1 = -((m1 >> 8) * 961 + ((m1 >> 4) & 15) * 31 + (m1 & 15));
        float bv0[4], bv1[4];
#pragma unroll
        for (int r = 0; r < 4; ++r) {
            bv0[r] = bt[qidx[r] + koff0];
            bv1[r] = bt[qidx[r] + koff1];
        }
        f32x4 s0 = mfma16(qf, kf0, cinit);
        f32x4 s1 = mfma16(qf, kf1, cinit);
#pragma unroll
        for (int r = 0; r < 4; ++r) {
            float p0 = fast_exp2(s0[r] + bv0[r]);
            float p1 = fast_exp2(s1[r] + bv1[r]);
            lsum[r] += p0 + p1;
            int row = lg * 4 + r;
            // XOR-swizzled store: chunk' = chunk ^ (row>>2) keeps ds_read_b128 16B-aligned
            pb[row * 48 + (((lm >> 3) ^ lg) << 3) + (lm & 7)]       = (__bf16)p0;
            pb[row * 48 + ((((lm >> 3) + 2) ^ lg) << 3) + (lm & 7)] = (__bf16)p1;
        }
        // P fragment: row=lm, chunk lg -> swizzled chunk lg ^ (lm>>2)
        bf16x8 pf  = *(const bf16x8*)(pb + lm * 48 + ((lg ^ (lm >> 2)) << 3));
        bf16x8 vf0 = *(const bf16x8*)(vbase + (size_t)lm * NTOK + t0 + lk);
        bf16x8 vf1 = *(const bf16x8*)(vbase + (size_t)(16 + lm) * NTOK + t0 + lk);
        o0 = mfma16(pf, vf0, o0);
        o1 = mfma16(pf, vf1, o1);
    }
#pragma unroll
    for (int r = 0; r < 4; ++r) {
        float l = lsum[r];
        l += __shfl_xor(l, 1);
        l += __shfl_xor(l, 2);
        l += __shfl_xor(l, 4);
        l += __shfl_xor(l, 8);
        float inv = 1.0f / l;
        int row = qrow0 + lg * 4 + r;
        size_t base = ((size_t)b_ * 2048 + row) * 256 + h * 32;
        attn[base + lm]      = (__bf16)(o0[r] * inv);
        attn[base + 16 + lm] = (__bf16)(o1[r] * inv);
    }
}

// ---------------- kernel 3: output projection -> fp32 ----------------
// wave computes a 16x64 strip: mt in [0,512), ng in [0,4)
__global__ __launch_bounds__(256) void k_out(const __bf16* __restrict__ attn,
                                             const __bf16* __restrict__ woT,
                                             float* __restrict__ out) {
    int wid = blockIdx.x * 4 + (threadIdx.x >> 6);   // 0..2047
    int lane = threadIdx.x & 63;
    int ng = wid & 3, mt = wid >> 2;
    int lm = lane & 15, lg = lane >> 4, lk = lg * 8;
    int nc0 = ng * 64;

    f32x4 acc[4];
#pragma unroll
    for (int j = 0; j < 4; ++j) acc[j] = (f32x4){0.f, 0.f, 0.f, 0.f};

    const __bf16* arow = attn + (size_t)(mt * 16 + lm) * 256 + lk;
    const __bf16* brow = woT + (size_t)(nc0 + lm) * 256 + lk;
#pragma unroll
    for (int kk = 0; kk < 8; ++kk) {
        bf16x8 a = *(const bf16x8*)(arow + kk * 32);
#pragma unroll
        for (int j = 0; j < 4; ++j) {
            bf16x8 b = *(const bf16x8*)(brow + (size_t)j * 16 * 256 + kk * 32);
            acc[j] = mfma16(a, b, acc[j]);
        }
    }
#pragma unroll
    for (int j = 0; j < 4; ++j) {
        int col = nc0 + j * 16 + lm;
#pragma unroll
        for (int r = 0; r < 4; ++r) {
            int row = mt * 16 + lg * 4 + r;
            out[(size_t)row * 256 + col] = acc[j][r];
        }
    }
}

extern "C" void kernel_launch(void* const* d_in, const int* in_sizes, int n_in,
                              void* d_out, int out_size, void* d_ws, size_t ws_size,
                              hipStream_t stream) {
    const float* x    = (const float*)d_in[0];
    const float* Wq   = (const float*)d_in[1];
    const float* Wk   = (const float*)d_in[2];
    const float* Wv   = (const float*)d_in[3];
    const float* Wo   = (const float*)d_in[4];
    const float* bias = (const float*)d_in[5];
    float* out = (float*)d_out;

    __bf16* ws  = (__bf16*)d_ws;
    __bf16* xb  = ws;                       // 8192*256 = 2,097,152  (reused as att)
    __bf16* wqT = xb  + 2097152;            // 65536
    __bf16* wkT = wqT + 65536;
    __bf16* wvT = wkT + 65536;
    __bf16* woT = wvT + 65536;
    __bf16* qb  = woT + 65536;              // (b,h,n,32)
    __bf16* kb  = qb  + 2097152;            // (b,h,n,32)
    __bf16* vb  = kb  + 2097152;            // (b,h,32,n)  V transposed
    float*  btx = (float*)(vb + 2097152);   // 115320 fp32 (bias * log2e)
    __bf16* att = xb;                       // alias: xb dead after k_qkv

    k_cvt_x<<<2048, 256, 0, stream>>>(x, xb);
    k_cvt_w<<<1024, 256, 0, stream>>>(Wq, Wk, Wv, Wo, wqT, wkT, wvT, woT);
    k_cvt_bias<<<(NBIAS + 255) / 256, 256, 0, stream>>>(bias, btx);
    k_qkv<<<1536, 256, 0, stream>>>(xb, wqT, wkT, wvT, qb, kb, vb);
    k_attn<<<1024, 256, 0, stream>>>(qb, kb, vb, btx, att);
    k_out<<<512, 256, 0, stream>>>(att, woT, out);
}

// Round 4
// 148.478 us; speedup vs baseline: 1.3636x; 1.1033x over previous
//
#include <hip/hip_runtime.h>
#include <math.h>

#define HIDDEN 256
#define NHEADS 8
#define HEAD 32
#define NTOK 2048      // tokens per batch (8*16*16)
#define NBIAS 115320   // 8 * 15 * 31 * 31
#define HTAB 14415     // 15*31*31 per-head bias entries

typedef __attribute__((ext_vector_type(8))) __bf16 bf16x8;
typedef __attribute__((ext_vector_type(4))) float f32x4;
typedef __attribute__((ext_vector_type(16))) float f32x16;
typedef __attribute__((ext_vector_type(4))) unsigned uint32x4;

static __device__ __forceinline__ f32x4 mfma16(bf16x8 a, bf16x8 b, f32x4 c) {
    return __builtin_amdgcn_mfma_f32_16x16x32_bf16(a, b, c, 0, 0, 0);
}
static __device__ __forceinline__ f32x16 mfma32(bf16x8 a, bf16x8 b, f32x16 c) {
    return __builtin_amdgcn_mfma_f32_32x32x16_bf16(a, b, c, 0, 0, 0);
}
static __device__ __forceinline__ float fexp2(float x) {
#if __has_builtin(__builtin_amdgcn_exp2f)
    return __builtin_amdgcn_exp2f(x);
#else
    return exp2f(x);
#endif
}
static __device__ __forceinline__ unsigned pkbf16(float a, float b) {
    unsigned short ua = __builtin_bit_cast(unsigned short, (__bf16)a);
    unsigned short ub = __builtin_bit_cast(unsigned short, (__bf16)b);
    return (unsigned)ua | ((unsigned)ub << 16);
}
static __device__ __forceinline__ float bflo(unsigned u) {   // low bf16 -> f32
    return __builtin_bit_cast(float, u << 16);
}
static __device__ __forceinline__ float bfhi(unsigned u) {   // high bf16 -> f32
    return __builtin_bit_cast(float, u & 0xffff0000u);
}

// ---------------- kernel 0a: x fp32 -> bf16 ----------------
__global__ void k_cvt_x(const float* __restrict__ x, __bf16* __restrict__ xb) {
    int i = (blockIdx.x * blockDim.x + threadIdx.x) * 4;
    float4 v = *(const float4*)(x + i);
    xb[i + 0] = (__bf16)v.x;
    xb[i + 1] = (__bf16)v.y;
    xb[i + 2] = (__bf16)v.z;
    xb[i + 3] = (__bf16)v.w;
}

// ---------------- kernel 0b: W fp32 -> bf16, transposed (N x K) ----------------
__global__ void k_cvt_w(const float* __restrict__ w0, const float* __restrict__ w1,
                        const float* __restrict__ w2, const float* __restrict__ w3,
                        __bf16* __restrict__ t0, __bf16* __restrict__ t1,
                        __bf16* __restrict__ t2, __bf16* __restrict__ t3) {
    int wsel = blockIdx.x >> 8;
    int i = (blockIdx.x & 255) * 256 + threadIdx.x;
    const float* w = (wsel == 0) ? w0 : (wsel == 1) ? w1 : (wsel == 2) ? w2 : w3;
    __bf16* t = (wsel == 0) ? t0 : (wsel == 1) ? t1 : (wsel == 2) ? t2 : t3;
    int n = i >> 8, k = i & 255;
    t[i] = (__bf16)w[k * 256 + n];       // t[n][k] = W[k][n]
}

// ---------------- kernel 0c: reversed bf16 bias quads, log2e folded ----------------
// bt4[head][i] = packed bf16 {bt[i], bt[i+1], bt[i+2], bt[i+3]} stored reversed:
// element r of a load at J-3 yields bt[J-r] (descending run for fragment regs r=0..3).
__global__ void k_cvt_bias4(const float* __restrict__ bias, uint2* __restrict__ bt4) {
    int i = blockIdx.x * 256 + threadIdx.x;
    if (i >= NBIAS) return;
    int head = i / HTAB;
    int off = i - head * HTAB;
    int b0 = head * HTAB;
    const float L2E = 1.4426950408889634f;
    int i3 = off + 3 > HTAB - 1 ? HTAB - 1 : off + 3;
    int i2 = off + 2 > HTAB - 1 ? HTAB - 1 : off + 2;
    int i1 = off + 1 > HTAB - 1 ? HTAB - 1 : off + 1;
    float e0 = bias[b0 + i3] * L2E;
    float e1 = bias[b0 + i2] * L2E;
    float e2 = bias[b0 + i1] * L2E;
    float e3 = bias[b0 + off] * L2E;
    bt4[i] = make_uint2(pkbf16(e0, e1), pkbf16(e2, e3));
}

// ---------------- kernel 1: fused QKV projection ----------------
__global__ __launch_bounds__(256) void k_qkv(const __bf16* __restrict__ xb,
                                             const __bf16* __restrict__ wqT,
                                             const __bf16* __restrict__ wkT,
                                             const __bf16* __restrict__ wvT,
                                             __bf16* __restrict__ qb,
                                             __bf16* __restrict__ kb,
                                             __bf16* __restrict__ vb) {
    int wid = blockIdx.x * 4 + (threadIdx.x >> 6);
    int lane = threadIdx.x & 63;
    int g = wid % 12, mt = wid / 12;
    int lm = lane & 15, lg = lane >> 4, lk = lg * 8;
    int which = g >> 2;
    int nc0 = (g & 3) * 64;
    const __bf16* wT = (which == 0) ? wqT : (which == 1) ? wkT : wvT;

    f32x4 acc[4];
#pragma unroll
    for (int j = 0; j < 4; ++j) acc[j] = (f32x4){0.f, 0.f, 0.f, 0.f};

    const __bf16* arow = xb + (size_t)(mt * 16 + lm) * 256 + lk;
    const __bf16* brow = wT + (size_t)(nc0 + lm) * 256 + lk;
#pragma unroll
    for (int kk = 0; kk < 8; ++kk) {
        bf16x8 a = *(const bf16x8*)(arow + kk * 32);
#pragma unroll
        for (int j = 0; j < 4; ++j) {
            bf16x8 b = *(const bf16x8*)(brow + (size_t)j * 16 * 256 + kk * 32);
            acc[j] = mfma16(a, b, acc[j]);
        }
    }
    const float QS = 0.17677669529663687f * 1.4426950408889634f;  // 1/sqrt(32) * log2(e)
#pragma unroll
    for (int j = 0; j < 4; ++j) {
        int col = nc0 + j * 16 + lm;
        int h = col >> 5, d = col & 31;
#pragma unroll
        for (int r = 0; r < 4; ++r) {
            int row = mt * 16 + lg * 4 + r;
            int b_ = row >> 11, n = row & 2047;
            if (which == 0)      qb[((size_t)(b_ * 8 + h) * 2048 + n) * 32 + d] = (__bf16)(acc[j][r] * QS);
            else if (which == 1) kb[((size_t)(b_ * 8 + h) * 2048 + n) * 32 + d] = (__bf16)acc[j][r];
            else                 vb[((size_t)(b_ * 8 + h) * 32 + d) * 2048 + n] = (__bf16)acc[j][r]; // V^T
        }
    }
}

// ---------------- kernel 2: attention, 32x32 swapped-operand, in-register softmax ----
// Block = one (b,h,q-strip of 32 rows); 4 waves = 4-way k-split (512 k each).
// S^T = mfma32(K, Q): lane q=lane&31 holds S[k][q] for 16 k (C row formula, m74/m101).
// P stays in-register; PV consumes it directly by loading V^T at the token order P
// naturally has per lane: A/B k-slot maps are identical, so any common permutation
// of tokens across slots is exact. No permlane, no LDS in the main loop.
// lsum via mfma32(ones, P). Fixed-reference softmax (scale cancels in O/lsum).
__global__ __launch_bounds__(256) void k_attn(const __bf16* __restrict__ qb,
                                              const __bf16* __restrict__ kb,
                                              const __bf16* __restrict__ vb,
                                              const uint2* __restrict__ bt4all,
                                              __bf16* __restrict__ attn) {
    int bid = blockIdx.x;
    int bh = bid >> 6;          // 0..31
    int qs = bid & 63;          // q-strip 0..63
    int b_ = bh >> 3, h = bh & 7;
    int w = threadIdx.x >> 6;   // wave = k-quarter
    int lane = threadIdx.x & 63;
    int lq = lane & 31;
    int hf = lane >> 5;
    int q0 = qs * 32;

    const __bf16* qbase = qb + (size_t)bh * NTOK * 32;
    const __bf16* kbase = kb + (size_t)bh * NTOK * 32;
    const __bf16* vbase = vb + (size_t)bh * 32 * NTOK;
    const uint2* bt4 = bt4all + h * HTAB;

    // Q B-frags (col=lane&31=q, k=8*hf+j), d-chunks 0 and 1 — loop invariant
    bf16x8 qf0 = *(const bf16x8*)(qbase + (size_t)(q0 + lq) * 32 + hf * 8);
    bf16x8 qf1 = *(const bf16x8*)(qbase + (size_t)(q0 + lq) * 32 + 16 + hf * 8);

    int qg = q0 + lq;
    // loop-invariant part of bias index J (includes -4hf of the k-token code)
    int qidx4 = (qg >> 8) * 961 + ((qg >> 4) & 15) * 31 + (qg & 15) + 7207 - 4 * hf;

    f32x16 Oacc, Lacc;
#pragma unroll
    for (int j = 0; j < 16; ++j) { Oacc[j] = 0.f; Lacc[j] = 0.f; }

    bf16x8 ones;
#pragma unroll
    for (int j = 0; j < 8; ++j) ones[j] = (__bf16)1.0f;

    for (int it = 0; it < 16; ++it) {
        int t0 = w * 512 + it * 32;
        // code(t0): t0 multiple of 32 -> h(t0) even, +1 carry from c>=16 never overflows
        int c00 = (t0 >> 8) * 961 + ((t0 >> 4) & 15) * 31;
        int jb = qidx4 - c00;
        // reg group g covers k-tokens t0 + 4hf + 8g + r (+h-carry fold for g>=2):
        // bias idx = jb - {0,8,31,39}[g] - r; reversed quad load at idx(r=0) - 3
        uint2 bq0 = bt4[jb - 3];
        uint2 bq1 = bt4[jb - 11];
        uint2 bq2 = bt4[jb - 34];
        uint2 bq3 = bt4[jb - 42];
        // K A-frags (row=lane&31=k-token, k=8*hf+j), d-chunks 0,1
        const __bf16* kp = kbase + (size_t)(t0 + lq) * 32 + hf * 8;
        bf16x8 kf0 = *(const bf16x8*)(kp);
        bf16x8 kf1 = *(const bf16x8*)(kp + 16);
        // V^T A-frags, token order matched to P's in-lane layout:
        // element j <- token t0 + 4hf + 8*(j>>2) + (j&3)
        const __bf16* vp = vbase + (size_t)lq * NTOK + t0 + 4 * hf;
        uint2 va = *(const uint2*)(vp);        // tokens +0..3   (of 4hf base)
        uint2 vbq = *(const uint2*)(vp + 8);   // tokens +8..11
        uint2 vc = *(const uint2*)(vp + 16);   // tokens +16..19
        uint2 vd = *(const uint2*)(vp + 24);   // tokens +24..27
        uint32x4 vw0 = {va.x, va.y, vbq.x, vbq.y};
        uint32x4 vw1 = {vc.x, vc.y, vd.x, vd.y};
        bf16x8 vf0 = __builtin_bit_cast(bf16x8, vw0);
        bf16x8 vf1 = __builtin_bit_cast(bf16x8, vw1);

        // C init = bias (log2e folded); mfma adds QK * log2e/sqrt(32)
        f32x16 S;
        S[0]  = bflo(bq0.x); S[1]  = bfhi(bq0.x); S[2]  = bflo(bq0.y); S[3]  = bfhi(bq0.y);
        S[4]  = bflo(bq1.x); S[5]  = bfhi(bq1.x); S[6]  = bflo(bq1.y); S[7]  = bfhi(bq1.y);
        S[8]  = bflo(bq2.x); S[9]  = bfhi(bq2.x); S[10] = bflo(bq2.y); S[11] = bfhi(bq2.y);
        S[12] = bflo(bq3.x); S[13] = bfhi(bq3.x); S[14] = bflo(bq3.y); S[15] = bfhi(bq3.y);
        S = mfma32(kf0, qf0, S);
        S = mfma32(kf1, qf1, S);

        // P = exp2(S) -> bf16 pairs; word Wg holds tokens t0 + 4hf + 8g + {0,1},
        // Wg' (g'=g+1 odd) tokens ... + {2,3}. Fed directly as B-frag (see V order).
        unsigned W0 = pkbf16(fexp2(S[0]),  fexp2(S[1]));
        unsigned W1 = pkbf16(fexp2(S[2]),  fexp2(S[3]));
        unsigned W2 = pkbf16(fexp2(S[4]),  fexp2(S[5]));
        unsigned W3 = pkbf16(fexp2(S[6]),  fexp2(S[7]));
        unsigned W4 = pkbf16(fexp2(S[8]),  fexp2(S[9]));
        unsigned W5 = pkbf16(fexp2(S[10]), fexp2(S[11]));
        unsigned W6 = pkbf16(fexp2(S[12]), fexp2(S[13]));
        unsigned W7 = pkbf16(fexp2(S[14]), fexp2(S[15]));
        uint32x4 pw0 = {W0, W1, W2, W3};
        uint32x4 pw1 = {W4, W5, W6, W7};
        bf16x8 pf0 = __builtin_bit_cast(bf16x8, pw0);
        bf16x8 pf1 = __builtin_bit_cast(bf16x8, pw1);

        Oacc = mfma32(vf0, pf0, Oacc);   // O^T[d][q] += V^T . P (common token perm)
        Oacc = mfma32(vf1, pf1, Oacc);
        Lacc = mfma32(ones, pf0, Lacc);  // every reg = lsum[q] partial
        Lacc = mfma32(ones, pf1, Lacc);
    }

    // ---- combine 4 k-partials via LDS ----
    __shared__ float part[4][64][20];   // 17 used (16 O + 1 lsum); stride 80B
#pragma unroll
    for (int j = 0; j < 4; ++j) {
        float4 t;
        t.x = Oacc[4 * j]; t.y = Oacc[4 * j + 1]; t.z = Oacc[4 * j + 2]; t.w = Oacc[4 * j + 3];
        *(float4*)&part[w][lane][4 * j] = t;
    }
    part[w][lane][16] = Lacc[0];
    __syncthreads();

    float4 o = {0.f, 0.f, 0.f, 0.f};
    float ls = 0.f;
#pragma unroll
    for (int sw = 0; sw < 4; ++sw) {
        float4 t = *(const float4*)&part[sw][lane][4 * w];
        o.x += t.x; o.y += t.y; o.z += t.z; o.w += t.w;
        ls += part[sw][lane][16];
    }
    float inv = 1.0f / ls;
    // wave w keeps regs 4w..4w+3 -> d = r + 8w + 4hf
    unsigned lo = pkbf16(o.x * inv, o.y * inv);
    unsigned hi = pkbf16(o.z * inv, o.w * inv);
    size_t base = ((size_t)b_ * NTOK + q0 + lq) * 256 + h * 32 + 8 * w + 4 * hf;
    *(uint2*)(attn + base) = make_uint2(lo, hi);
}

// ---------------- kernel 3: output projection -> fp32 ----------------
__global__ __launch_bounds__(256) void k_out(const __bf16* __restrict__ attn,
                                             const __bf16* __restrict__ woT,
                                             float* __restrict__ out) {
    int wid = blockIdx.x * 4 + (threadIdx.x >> 6);
    int lane = threadIdx.x & 63;
    int ng = wid & 3, mt = wid >> 2;
    int lm = lane & 15, lg = lane >> 4, lk = lg * 8;
    int nc0 = ng * 64;

    f32x4 acc[4];
#pragma unroll
    for (int j = 0; j < 4; ++j) acc[j] = (f32x4){0.f, 0.f, 0.f, 0.f};

    const __bf16* arow = attn + (size_t)(mt * 16 + lm) * 256 + lk;
    const __bf16* brow = woT + (size_t)(nc0 + lm) * 256 + lk;
#pragma unroll
    for (int kk = 0; kk < 8; ++kk) {
        bf16x8 a = *(const bf16x8*)(arow + kk * 32);
#pragma unroll
        for (int j = 0; j < 4; ++j) {
            bf16x8 b = *(const bf16x8*)(brow + (size_t)j * 16 * 256 + kk * 32);
            acc[j] = mfma16(a, b, acc[j]);
        }
    }
#pragma unroll
    for (int j = 0; j < 4; ++j) {
        int col = nc0 + j * 16 + lm;
#pragma unroll
        for (int r = 0; r < 4; ++r) {
            int row = mt * 16 + lg * 4 + r;
            out[(size_t)row * 256 + col] = acc[j][r];
        }
    }
}

extern "C" void kernel_launch(void* const* d_in, const int* in_sizes, int n_in,
                              void* d_out, int out_size, void* d_ws, size_t ws_size,
                              hipStream_t stream) {
    const float* x    = (const float*)d_in[0];
    const float* Wq   = (const float*)d_in[1];
    const float* Wk   = (const float*)d_in[2];
    const float* Wv   = (const float*)d_in[3];
    const float* Wo   = (const float*)d_in[4];
    const float* bias = (const float*)d_in[5];
    float* out = (float*)d_out;

    __bf16* ws  = (__bf16*)d_ws;
    __bf16* xb  = ws;                       // 2,097,152 bf16 (reused as att)
    __bf16* wqT = xb  + 2097152;
    __bf16* wkT = wqT + 65536;
    __bf16* wvT = wkT + 65536;
    __bf16* woT = wvT + 65536;
    __bf16* qb  = woT + 65536;              // (b,h,n,32)
    __bf16* kb  = qb  + 2097152;            // (b,h,n,32)
    __bf16* vb  = kb  + 2097152;            // (b,h,32,n)  V^T
    uint2*  bt4 = (uint2*)(vb + 2097152);   // 115320 x 8B packed bias quads
    __bf16* att = xb;                       // alias: xb dead after k_qkv

    k_cvt_x<<<2048, 256, 0, stream>>>(x, xb);
    k_cvt_w<<<1024, 256, 0, stream>>>(Wq, Wk, Wv, Wo, wqT, wkT, wvT, woT);
    k_cvt_bias4<<<(NBIAS + 255) / 256, 256, 0, stream>>>(bias, bt4);
    k_qkv<<<1536, 256, 0, stream>>>(xb, wqT, wkT, wvT, qb, kb, vb);
    k_attn<<<2048, 256, 0, stream>>>(qb, kb, vb, bt4, att);
    k_out<<<512, 256, 0, stream>>>(att, woT, out);
}